// Round 1
// baseline (27903.833 us; speedup 1.0000x reference)
//
#include <hip/hip_runtime.h>
#include <hip/hip_bf16.h>
#include <hip/hip_cooperative_groups.h>
#include <math.h>

namespace cg = cooperative_groups;

// xLSTM forward on MI355X (gfx950).
// Recurrence is now ONE persistent cooperative kernel per block (192 WGs):
//   - blocks 0..63   : layer0, 16 cell-cols each, Whh0 slice (128 KB) in LDS
//   - blocks 64..191 : layer1,  8 cell-cols each, Wih1+Whh1 slices (128 KB) in LDS
// Weights staged once (XOR-swizzled rows for conflict-free ds_read_b128),
// c-state lives in registers, one grid.sync() per tick (257 ticks).
// h sequences: [slot][b][1024] bf16, slot s holds h[s-1] (slot 0 = zeros).

typedef __bf16 bf16x8 __attribute__((ext_vector_type(8)));
typedef __bf16 bf16x4 __attribute__((ext_vector_type(4)));
typedef float floatx4 __attribute__((ext_vector_type(4)));

__device__ __forceinline__ float sigmf(float x){ return 1.0f/(1.0f+expf(-x)); }

// ---------- f32 -> bf16 weight conversion (4 elems/thread) ----------
__global__ __launch_bounds__(256) void cvt_kernel(const float* __restrict__ src,
                                                  __bf16* __restrict__ dst, int n4){
  int i = blockIdx.x*256 + threadIdx.x;
  if (i >= n4) return;
  float4 v = ((const float4*)src)[i];
  bf16x4 o = { (__bf16)v.x, (__bf16)v.y, (__bf16)v.z, (__bf16)v.w };
  ((bf16x4*)dst)[i] = o;
}

// ---------- embedding gather: x[s*16+b][:] = emb[seq[b][s]][:] ----------
__global__ __launch_bounds__(256) void gather_kernel(const int* __restrict__ seq,
    const float* __restrict__ emb, float* __restrict__ x, __bf16* __restrict__ xbf){
  int r = blockIdx.x;                 // 0..4095, s = r>>4, b = r&15
  int tid = threadIdx.x;
  int tok = seq[((r&15)<<8) + (r>>4)];
  float4 v = *(const float4*)(emb + (size_t)tok*1024 + (tid<<2));
  *(float4*)(x + ((size_t)r<<10) + (tid<<2)) = v;
  bf16x4 o = { (__bf16)v.x, (__bf16)v.y, (__bf16)v.z, (__bf16)v.w };
  *(bf16x4*)(xbf + ((size_t)r<<10) + (tid<<2)) = o;
}

// ---------- generic bf16 MFMA GEMM: C[M=4096, N] = A[4096,1024] @ B[N,1024]^T ----------
// mode 0: out = acc + bias[col]                       (f32, row-major)
// mode 1: out = gelu_exact(acc + bias[col])           (f32, row-major)
// mode 2: out[(b*256+s)*N + col] = acc + bias[col]    (logits, [B,S,V] remap)
__global__ __launch_bounds__(256) void gemm_kernel(const __bf16* __restrict__ A,
    const __bf16* __restrict__ Bw, const float* __restrict__ bias,
    float* __restrict__ out, int N, int mode){
  const int K = 1024;
  __shared__ __align__(16) __bf16 As[64][40];   // +8 pad -> 80B row stride, 2-way max
  __shared__ __align__(16) __bf16 Bs[64][40];
  int m0 = blockIdx.y<<6, n0 = blockIdx.x<<6;
  int tid = threadIdx.x, w = tid>>6, lane = tid&63, quad = lane>>4, ln = lane&15;
  int lrow = tid>>2, lcg = (tid&3)<<3;
  const __bf16* ag = A  + (size_t)(m0+lrow)*K + lcg;
  const __bf16* bg = Bw + (size_t)(n0+lrow)*K + lcg;
  floatx4 acc[4] = {{0.f,0.f,0.f,0.f},{0.f,0.f,0.f,0.f},{0.f,0.f,0.f,0.f},{0.f,0.f,0.f,0.f}};
  for (int kk = 0; kk < K; kk += 32){
    uint4 av = *(const uint4*)(ag + kk);
    uint4 bv = *(const uint4*)(bg + kk);
    __syncthreads();
    *(uint4*)&As[lrow][lcg] = av;
    *(uint4*)&Bs[lrow][lcg] = bv;
    __syncthreads();
    bf16x8 af = *(const bf16x8*)&As[(w<<4)+ln][quad<<3];
#pragma unroll
    for (int nt = 0; nt < 4; nt++){
      bf16x8 bf_ = *(const bf16x8*)&Bs[(nt<<4)+ln][quad<<3];
      acc[nt] = __builtin_amdgcn_mfma_f32_16x16x32_bf16(af, bf_, acc[nt], 0, 0, 0);
    }
  }
#pragma unroll
  for (int nt = 0; nt < 4; nt++){
    int col = n0 + (nt<<4) + ln;
    float bv = bias[col];
#pragma unroll
    for (int r = 0; r < 4; r++){
      int row = m0 + (w<<4) + (quad<<2) + r;   // D layout: row = quad*4+reg, col = lane&15
      float v = acc[nt][r] + bv;
      if (mode == 1) v = 0.5f*v*(1.0f + erff(v*0.70710678118f));
      size_t oidx;
      if (mode == 2){ int s = row>>4, b = row&15; oidx = ((size_t)((b<<8)+s))*N + col; }
      else oidx = (size_t)row*N + col;
      out[oidx] = v;
    }
  }
}

// ---------- persistent recurrence kernel (cooperative, 192 blocks x 256 thr) ----------
// LDS: Wl = 128 KB weight slice ([64 rows][1024 K] bf16, row-XOR-swizzled),
//      red = 17 KB K-split reduction buffer ([16][17]-padded f32 tiles).
// Per tick: each wave MFMAs its K=256 slice against LDS weights, partials reduced
// through LDS, gate nonlinearity per-thread with register-resident c-state,
// 16x(16|8) bf16 h-tile written to global, then grid-wide barrier.
__global__ __launch_bounds__(256, 1) void rec_kernel(
    const __bf16* __restrict__ Whh0, const __bf16* __restrict__ Wih1,
    const __bf16* __restrict__ Whh1, const float* __restrict__ bg1,
    const float* __restrict__ ih, __bf16* __restrict__ h0seq,
    __bf16* __restrict__ h1seq){
  __shared__ __align__(16) __bf16 Wl[65536];   // 128 KB
  __shared__ float red[4352];                   // 16 tiles x [16][17] f32
  cg::grid_group grid = cg::this_grid();

  const int tid  = threadIdx.x;
  const int w    = tid >> 6, lane = tid & 63, quad = lane >> 4, ln = lane & 15;
  const int bid  = blockIdx.x;
  const bool is0 = (bid < 64);

  // ---- stage weight slice into LDS, once (row-major, byte ^= (row&7)<<4) ----
  if (is0){
    const int j0 = bid << 4;
    for (int c = tid; c < 8192; c += 256){
      int rl = c >> 7, ks = c & 127;               // LDS row, 16B chunk within row
      int g = rl >> 4, jc = rl & 15;               // row rl = gate g, col j0+jc
      uint4 v = *(const uint4*)(Whh0 + (size_t)((g<<10) + j0 + jc)*1024 + (ks<<3));
      *(uint4*)((char*)Wl + rl*2048 + ((ks<<4) ^ ((rl&7)<<4))) = v;
    }
  } else {
    const int j0 = (bid - 64) << 3;
    for (int c = tid; c < 8192; c += 256){
      int rl = c >> 7, ks = c & 127;
      // rl = m*32 + t2*16 + p ; p = g*4 + jl ; global row = g*1024 + j0 + t2*4 + jl
      int m = rl >> 5, t2 = (rl >> 4) & 1, p = rl & 15, g = p >> 2, jl = p & 3;
      const __bf16* base = m ? Whh1 : Wih1;
      uint4 v = *(const uint4*)(base + (size_t)((g<<10) + j0 + (t2<<2) + jl)*1024 + (ks<<3));
      *(uint4*)((char*)Wl + rl*2048 + ((ks<<4) ^ ((rl&7)<<4))) = v;
    }
  }
  __syncthreads();

  float creg = 0.0f;   // register-resident cell state (one cell per thread)

  if (is0){
    // ---------------- layer 0: computes h0[t] at tick t (t<256) ----------------
    const int j0 = bid << 4;
    const int row = tid >> 4, jc = tid & 15;       // this thread's cell
    for (int t = 0; t <= 256; ++t){
      if (t < 256){
        float ihv[4];                               // ih already includes bg0
        const float* ip = ih + (size_t)((t<<4) + row)*4096 + j0 + jc;
#pragma unroll
        for (int g = 0; g < 4; ++g) ihv[g] = ip[(size_t)g<<10];
        const __bf16* ha = h0seq + ((size_t)t << 14);   // h0[t-1]
        floatx4 acc[4] = {{0,0,0,0},{0,0,0,0},{0,0,0,0},{0,0,0,0}};
#pragma unroll
        for (int kk = 0; kk < 8; ++kk){
          int k0 = (w<<8) + (kk<<5);                // this wave's K slice
          bf16x8 a = *(const bf16x8*)(ha + ((size_t)ln<<10) + k0 + (quad<<3));
#pragma unroll
          for (int g = 0; g < 4; ++g){
            int rl = (g<<4) + ln;
            bf16x8 b = *(const bf16x8*)((const char*)Wl + rl*2048
                         + (((k0<<1) + (quad<<4)) ^ ((rl&7)<<4)));
            acc[g] = __builtin_amdgcn_mfma_f32_16x16x32_bf16(a, b, acc[g], 0, 0, 0);
          }
        }
#pragma unroll
        for (int g = 0; g < 4; ++g)
#pragma unroll
          for (int r = 0; r < 4; ++r)
            red[((w<<2)+g)*272 + ((quad<<2)+r)*17 + ln] = acc[g][r];
        __syncthreads();
        float gate[4];
#pragma unroll
        for (int g = 0; g < 4; ++g){
          float s = ihv[g];
#pragma unroll
          for (int w2 = 0; w2 < 4; ++w2) s += red[((w2<<2)+g)*272 + row*17 + jc];
          gate[g] = s;
        }
        float cn = sigmf(gate[1])*creg + expf(gate[0])*tanhf(gate[2]);
        float hn = sigmf(gate[3])*tanhf(cn);
        creg = cn;
        h0seq[((size_t)(t+1)<<14) + ((size_t)row<<10) + j0 + jc] = (__bf16)hn;
      }
      __threadfence();
      grid.sync();
      __threadfence();
    }
  } else {
    // ------------- layer 1: computes h1[t-1] at tick t (t>=1), slot t -------------
    const int j0 = (bid - 64) << 3;
    const int row = tid >> 3, jc = tid & 7;        // valid for tid<128
    const int t2c = jc >> 2, jl = jc & 3;
    float bgv[4] = {0,0,0,0};
    if (tid < 128){
#pragma unroll
      for (int g = 0; g < 4; ++g) bgv[g] = bg1[(g<<10) + j0 + jc];
    }
    for (int t = 0; t <= 256; ++t){
      if (t >= 1){
        const __bf16* ha = h0seq + ((size_t)t << 14);       // h0[t-1]
        const __bf16* hb = h1seq + ((size_t)(t-1) << 14);   // h1[t-2]
        floatx4 acc[2] = {{0,0,0,0},{0,0,0,0}};
#pragma unroll
        for (int kk = 0; kk < 8; ++kk){
          int k0 = (w<<8) + (kk<<5);
          bf16x8 a0 = *(const bf16x8*)(ha + ((size_t)ln<<10) + k0 + (quad<<3));
          bf16x8 a1 = *(const bf16x8*)(hb + ((size_t)ln<<10) + k0 + (quad<<3));
#pragma unroll
          for (int t2 = 0; t2 < 2; ++t2){
            int rlA = (t2<<4) + ln;                 // Wih rows
            bf16x8 b0 = *(const bf16x8*)((const char*)Wl + rlA*2048
                          + (((k0<<1) + (quad<<4)) ^ ((rlA&7)<<4)));
            acc[t2] = __builtin_amdgcn_mfma_f32_16x16x32_bf16(a0, b0, acc[t2], 0, 0, 0);
            int rlB = 32 + (t2<<4) + ln;            // Whh rows
            bf16x8 b1 = *(const bf16x8*)((const char*)Wl + rlB*2048
                          + (((k0<<1) + (quad<<4)) ^ ((rlB&7)<<4)));
            acc[t2] = __builtin_amdgcn_mfma_f32_16x16x32_bf16(a1, b1, acc[t2], 0, 0, 0);
          }
        }
#pragma unroll
        for (int t2 = 0; t2 < 2; ++t2)
#pragma unroll
          for (int r = 0; r < 4; ++r)
            red[((w<<1)+t2)*272 + ((quad<<2)+r)*17 + ln] = acc[t2][r];
        __syncthreads();
        if (tid < 128){
          float gate[4];
#pragma unroll
          for (int g = 0; g < 4; ++g){
            int p = (g<<2) + jl;
            float s = bgv[g];
#pragma unroll
            for (int w2 = 0; w2 < 4; ++w2) s += red[((w2<<1)+t2c)*272 + row*17 + p];
            gate[g] = s;
          }
          float cn = sigmf(gate[1])*creg + expf(gate[0])*tanhf(gate[2]);
          float hn = sigmf(gate[3])*tanhf(cn);
          creg = cn;
          h1seq[((size_t)t<<14) + ((size_t)row<<10) + j0 + jc] = (__bf16)hn;
        }
      }
      __threadfence();
      grid.sync();
      __threadfence();
    }
  }
}

// ---------- residual + layernorm (writes x f32 and bf16 in place) ----------
__global__ __launch_bounds__(256) void ln_kernel(const float* __restrict__ y,
    float* __restrict__ x, __bf16* __restrict__ xbf,
    const float* __restrict__ g, const float* __restrict__ b){
  int row = blockIdx.x, tid = threadIdx.x, lane = tid&63, w = tid>>6;
  size_t base = (size_t)row<<10;
  int k = tid<<2;
  float4 yv = *(const float4*)(y + base + k);
  float4 xv = *(const float4*)(x + base + k);
  float4 u = { yv.x+xv.x, yv.y+xv.y, yv.z+xv.z, yv.w+xv.w };
  float s = u.x+u.y+u.z+u.w;
  float q = u.x*u.x + u.y*u.y + u.z*u.z + u.w*u.w;
  for (int off = 32; off > 0; off >>= 1){
    s += __shfl_down(s, off, 64);
    q += __shfl_down(q, off, 64);
  }
  __shared__ float ss[4], qq[4];
  if (lane == 0){ ss[w] = s; qq[w] = q; }
  __syncthreads();
  float ts = ss[0]+ss[1]+ss[2]+ss[3];
  float tq = qq[0]+qq[1]+qq[2]+qq[3];
  float mean = ts*(1.0f/1024.0f);
  float var  = tq*(1.0f/1024.0f) - mean*mean;
  float inv  = rsqrtf(var + 1e-5f);
  float4 gv = *(const float4*)(g + k);
  float4 bv = *(const float4*)(b + k);
  float4 o = { (u.x-mean)*inv*gv.x + bv.x, (u.y-mean)*inv*gv.y + bv.y,
               (u.z-mean)*inv*gv.z + bv.z, (u.w-mean)*inv*gv.w + bv.w };
  *(float4*)(x + base + k) = o;
  bf16x4 ob = { (__bf16)o.x, (__bf16)o.y, (__bf16)o.z, (__bf16)o.w };
  *(bf16x4*)(xbf + base + k) = ob;
}

extern "C" void kernel_launch(void* const* d_in, const int* in_sizes, int n_in,
                              void* d_out, int out_size, void* d_ws, size_t ws_size,
                              hipStream_t stream){
  const int*   seq = (const int*)d_in[0];
  const float* emb = (const float*)d_in[1];
  const float* Wih = (const float*)d_in[2];
  const float* Whh = (const float*)d_in[3];
  const float* bg  = (const float*)d_in[4];
  const float* pW  = (const float*)d_in[5];
  const float* pb  = (const float*)d_in[6];
  const float* lng = (const float*)d_in[7];
  const float* lnb = (const float*)d_in[8];
  const float* oW  = (const float*)d_in[9];
  const float* ob  = (const float*)d_in[10];
  float* out = (float*)d_out;

  char* ws = (char*)d_ws;
  size_t off = 0;
  auto alloc = [&](size_t bytes)->char*{
    char* p = ws + off; off += (bytes + 255) & ~(size_t)255; return p;
  };
  __bf16* wih_bf = (__bf16*)alloc(16777216ULL*2);   // [2][2][4096][1024]
  __bf16* whh_bf = (__bf16*)alloc(16777216ULL*2);
  __bf16* pw_bf  = (__bf16*)alloc(2097152ULL*2);    // [2][1024][1024]
  __bf16* ow_bf  = (__bf16*)alloc(32768000ULL*2);   // [32000][1024]
  float*  x      = (float*)alloc(4194304ULL*4);     // [4096][1024] f32
  __bf16* xbf    = (__bf16*)alloc(4194304ULL*2);
  float*  ihb    = (float*)alloc(16777216ULL*4);    // [256][16][4096] f32
  __bf16* h0seq  = (__bf16*)alloc(257ULL*16384*2);  // [257][16][1024]
  __bf16* h1seq  = (__bf16*)alloc(257ULL*16384*2);
  float*  y      = (float*)alloc(4194304ULL*4);     // [4096][1024] f32

  cvt_kernel<<<16384, 256, 0, stream>>>(Wih, wih_bf, 4194304);
  cvt_kernel<<<16384, 256, 0, stream>>>(Whh, whh_bf, 4194304);
  cvt_kernel<<<2048,  256, 0, stream>>>(pW,  pw_bf,  524288);
  cvt_kernel<<<32000, 256, 0, stream>>>(oW,  ow_bf,  8192000);
  gather_kernel<<<4096, 256, 0, stream>>>(seq, emb, x, xbf);
  hipMemsetAsync(h0seq, 0, 16384*2, stream);   // slot 0 = zeros (stays zero)
  hipMemsetAsync(h1seq, 0, 16384*2, stream);

  for (int blk = 0; blk < 2; blk++){
    const __bf16* wih0 = wih_bf + (size_t)blk*2*4194304;
    const __bf16* wih1 = wih0 + 4194304;
    const __bf16* whh0 = whh_bf + (size_t)blk*2*4194304;
    const __bf16* whh1 = whh0 + 4194304;
    const float*  bg0  = bg + blk*2*4096;
    const float*  bg1  = bg0 + 4096;
    // ih0 = x @ Wih0^T + bg0  (layer-0 input projection, parallel over S)
    gemm_kernel<<<dim3(64,64), 256, 0, stream>>>(xbf, wih0, bg0, ihb, 4096, 0);
    // persistent recurrence: 257 ticks, weights LDS-resident, c-state in regs
    {
      const __bf16* p_whh0 = whh0;
      const __bf16* p_wih1 = wih1;
      const __bf16* p_whh1 = whh1;
      const float*  p_bg1  = bg1;
      const float*  p_ih   = ihb;
      __bf16* p_h0 = h0seq;
      __bf16* p_h1 = h1seq;
      void* kargs[] = { &p_whh0, &p_wih1, &p_whh1, &p_bg1, &p_ih, &p_h0, &p_h1 };
      hipLaunchCooperativeKernel((const void*)rec_kernel, dim3(192), dim3(256),
                                 kargs, 0, stream);
    }
    // y = gelu(h1 @ pW^T + pb); h1seq+16384 is dense [4096][1024] row-major
    gemm_kernel<<<dim3(16,64), 256, 0, stream>>>(h1seq + 16384, pw_bf + (size_t)blk*1048576,
                                                 pb + blk*1024, y, 1024, 1);
    ln_kernel<<<4096, 256, 0, stream>>>(y, x, xbf, lng + blk*1024, lnb + blk*1024);
  }
  // logits = x @ out_W^T + out_b, remapped to [B,S,V]
  gemm_kernel<<<dim3(500,64), 256, 0, stream>>>(xbf, ow_bf, ob, out, 32000, 2);
}

// Round 3
// 4760.035 us; speedup vs baseline: 5.8621x; 5.8621x over previous
//
#include <hip/hip_runtime.h>
#include <hip/hip_bf16.h>
#include <math.h>

// xLSTM forward on MI355X (gfx950).
// Recurrence: ONE persistent cooperative kernel per block (192 WGs):
//   - blocks 0..63   : layer0, 16 cell-cols each, Whh0 slice (128 KB) in LDS
//   - blocks 64..191 : layer1,  8 cell-cols each, Wih1+Whh1 slices (128 KB) in LDS
// Cross-block h traffic uses sc0/sc1 (coherence-point) loads/stores, so the
// per-tick grid barrier needs NO cache flushes: relaxed agent-scope counter +
// generation word, one release store per tick total.
// h sequences: [slot][b][1024] bf16, slot s holds h[s-1] (slot 0 = zeros).

typedef __bf16 bf16x8 __attribute__((ext_vector_type(8)));
typedef __bf16 bf16x4 __attribute__((ext_vector_type(4)));
typedef float floatx4 __attribute__((ext_vector_type(4)));

__device__ __forceinline__ float sigmf(float x){ return 1.0f/(1.0f+expf(-x)); }

// ---- coherence-point accesses (bypass non-coherent L1/L2; cross-XCD safe) ----
__device__ __forceinline__ bf16x8 ld_coh(const __bf16* p){
  bf16x8 r;
  asm volatile("global_load_dwordx4 %0, %1, off sc0 sc1"
               : "=&v"(r) : "v"((unsigned long long)p));
  return r;   // NOT valid until s_waitcnt vmcnt(0)
}
__device__ __forceinline__ void st_coh2(__bf16* p, unsigned bits){
  asm volatile("global_store_short %0, %1, off sc0 sc1"
               :: "v"((unsigned long long)p), "v"(bits) : "memory");
}

// ---- flush-free grid barrier (cooperative launch guarantees co-residency) ----
// cnt at bar[0], gen at bar[32] (separate cachelines). All h stores are sc0/sc1,
// so a per-wave vmcnt(0) drain makes them globally visible before arrival; no
// buffer_wbl2/buffer_inv needed anywhere in the loop.
__device__ __forceinline__ void gridbar(unsigned* bar, unsigned target, int tid, int nblk){
  asm volatile("s_waitcnt vmcnt(0)" ::: "memory");
  __syncthreads();
  if (tid == 0){
    unsigned prev = __hip_atomic_fetch_add(bar, 1u, __ATOMIC_RELAXED, __HIP_MEMORY_SCOPE_AGENT);
    if (prev == (unsigned)(nblk - 1)){
      __hip_atomic_store(bar, 0u, __ATOMIC_RELAXED, __HIP_MEMORY_SCOPE_AGENT);
      // release orders the counter reset (and everything else) before publish
      __hip_atomic_store(bar + 32, target, __ATOMIC_RELEASE, __HIP_MEMORY_SCOPE_AGENT);
    } else {
      while (__hip_atomic_load(bar + 32, __ATOMIC_RELAXED, __HIP_MEMORY_SCOPE_AGENT) != target)
        __builtin_amdgcn_s_sleep(2);
    }
  }
  __syncthreads();
}

// ---------- f32 -> bf16 weight conversion (4 elems/thread) ----------
__global__ __launch_bounds__(256) void cvt_kernel(const float* __restrict__ src,
                                                  __bf16* __restrict__ dst, int n4){
  int i = blockIdx.x*256 + threadIdx.x;
  if (i >= n4) return;
  float4 v = ((const float4*)src)[i];
  bf16x4 o = { (__bf16)v.x, (__bf16)v.y, (__bf16)v.z, (__bf16)v.w };
  ((bf16x4*)dst)[i] = o;
}

// ---------- embedding gather: x[s*16+b][:] = emb[seq[b][s]][:] ----------
__global__ __launch_bounds__(256) void gather_kernel(const int* __restrict__ seq,
    const float* __restrict__ emb, float* __restrict__ x, __bf16* __restrict__ xbf){
  int r = blockIdx.x;                 // 0..4095, s = r>>4, b = r&15
  int tid = threadIdx.x;
  int tok = seq[((r&15)<<8) + (r>>4)];
  float4 v = *(const float4*)(emb + (size_t)tok*1024 + (tid<<2));
  *(float4*)(x + ((size_t)r<<10) + (tid<<2)) = v;
  bf16x4 o = { (__bf16)v.x, (__bf16)v.y, (__bf16)v.z, (__bf16)v.w };
  *(bf16x4*)(xbf + ((size_t)r<<10) + (tid<<2)) = o;
}

// ---------- generic bf16 MFMA GEMM: C[M=4096, N] = A[4096,1024] @ B[N,1024]^T ----------
// mode 0: out = acc + bias[col]                       (f32, row-major)
// mode 1: out = gelu_exact(acc + bias[col])           (f32, row-major)
// mode 2: out[(b*256+s)*N + col] = acc + bias[col]    (logits, [B,S,V] remap)
__global__ __launch_bounds__(256) void gemm_kernel(const __bf16* __restrict__ A,
    const __bf16* __restrict__ Bw, const float* __restrict__ bias,
    float* __restrict__ out, int N, int mode){
  const int K = 1024;
  __shared__ __align__(16) __bf16 As[64][40];   // +8 pad -> 80B row stride, 2-way max
  __shared__ __align__(16) __bf16 Bs[64][40];
  int m0 = blockIdx.y<<6, n0 = blockIdx.x<<6;
  int tid = threadIdx.x, w = tid>>6, lane = tid&63, quad = lane>>4, ln = lane&15;
  int lrow = tid>>2, lcg = (tid&3)<<3;
  const __bf16* ag = A  + (size_t)(m0+lrow)*K + lcg;
  const __bf16* bg = Bw + (size_t)(n0+lrow)*K + lcg;
  floatx4 acc[4] = {{0.f,0.f,0.f,0.f},{0.f,0.f,0.f,0.f},{0.f,0.f,0.f,0.f},{0.f,0.f,0.f,0.f}};
  for (int kk = 0; kk < K; kk += 32){
    uint4 av = *(const uint4*)(ag + kk);
    uint4 bv = *(const uint4*)(bg + kk);
    __syncthreads();
    *(uint4*)&As[lrow][lcg] = av;
    *(uint4*)&Bs[lrow][lcg] = bv;
    __syncthreads();
    bf16x8 af = *(const bf16x8*)&As[(w<<4)+ln][quad<<3];
#pragma unroll
    for (int nt = 0; nt < 4; nt++){
      bf16x8 bf_ = *(const bf16x8*)&Bs[(nt<<4)+ln][quad<<3];
      acc[nt] = __builtin_amdgcn_mfma_f32_16x16x32_bf16(af, bf_, acc[nt], 0, 0, 0);
    }
  }
#pragma unroll
  for (int nt = 0; nt < 4; nt++){
    int col = n0 + (nt<<4) + ln;
    float bv = bias[col];
#pragma unroll
    for (int r = 0; r < 4; r++){
      int row = m0 + (w<<4) + (quad<<2) + r;   // D layout: row = quad*4+reg, col = lane&15
      float v = acc[nt][r] + bv;
      if (mode == 1) v = 0.5f*v*(1.0f + erff(v*0.70710678118f));
      size_t oidx;
      if (mode == 2){ int s = row>>4, b = row&15; oidx = ((size_t)((b<<8)+s))*N + col; }
      else oidx = (size_t)row*N + col;
      out[oidx] = v;
    }
  }
}

// ---------- persistent recurrence kernel (cooperative, 192 blocks x 256 thr) ----------
__global__ __launch_bounds__(256, 1) void rec_kernel(
    const __bf16* __restrict__ Whh0, const __bf16* __restrict__ Wih1,
    const __bf16* __restrict__ Whh1, const float* __restrict__ bg1,
    const float* __restrict__ ih, __bf16* __restrict__ h0seq,
    __bf16* __restrict__ h1seq, unsigned* bar){
  __shared__ __align__(16) __bf16 Wl[65536];   // 128 KB
  __shared__ float red[4352];                   // 16 tiles x [16][17] f32

  const int tid  = threadIdx.x;
  const int w    = tid >> 6, lane = tid & 63, quad = lane >> 4, ln = lane & 15;
  const int bid  = blockIdx.x;
  const bool is0 = (bid < 64);

  // ---- stage weight slice into LDS, once (row-major, byte ^= (row&7)<<4) ----
  if (is0){
    const int j0 = bid << 4;
    for (int c = tid; c < 8192; c += 256){
      int rl = c >> 7, ks = c & 127;               // LDS row, 16B chunk within row
      int g = rl >> 4, jc = rl & 15;               // row rl = gate g, col j0+jc
      uint4 v = *(const uint4*)(Whh0 + (size_t)((g<<10) + j0 + jc)*1024 + (ks<<3));
      *(uint4*)((char*)Wl + rl*2048 + ((ks<<4) ^ ((rl&7)<<4))) = v;
    }
  } else {
    const int j0 = (bid - 64) << 3;
    for (int c = tid; c < 8192; c += 256){
      int rl = c >> 7, ks = c & 127;
      // rl = m*32 + t2*16 + p ; p = g*4 + jl ; global row = g*1024 + j0 + t2*4 + jl
      int m = rl >> 5, t2 = (rl >> 4) & 1, p = rl & 15, g = p >> 2, jl = p & 3;
      const __bf16* base = m ? Whh1 : Wih1;
      uint4 v = *(const uint4*)(base + (size_t)((g<<10) + j0 + (t2<<2) + jl)*1024 + (ks<<3));
      *(uint4*)((char*)Wl + rl*2048 + ((ks<<4) ^ ((rl&7)<<4))) = v;
    }
  }
  __syncthreads();

  float creg = 0.0f;   // register-resident cell state (one cell per thread)

  if (is0){
    // ---------------- layer 0: computes h0[t] at tick t (t<256) ----------------
    const int j0 = bid << 4;
    const int row = tid >> 4, jc = tid & 15;       // this thread's cell
    for (int t = 0; t <= 256; ++t){
      if (t < 256){
        const __bf16* ha = h0seq + ((size_t)t << 14);   // h0[t-1]
        bf16x8 afr[8];
#pragma unroll
        for (int kk = 0; kk < 8; ++kk){
          int k0 = (w<<8) + (kk<<5);                // this wave's K slice
          afr[kk] = ld_coh(ha + ((size_t)ln<<10) + k0 + (quad<<3));
        }
        float ihv[4];                               // ih already includes bg0
        const float* ip = ih + (size_t)((t<<4) + row)*4096 + j0 + jc;
#pragma unroll
        for (int g = 0; g < 4; ++g) ihv[g] = ip[(size_t)g<<10];
        asm volatile("s_waitcnt vmcnt(0)" ::: "memory");
        __builtin_amdgcn_sched_barrier(0);
        floatx4 acc[4] = {{0,0,0,0},{0,0,0,0},{0,0,0,0},{0,0,0,0}};
#pragma unroll
        for (int kk = 0; kk < 8; ++kk){
          int k0 = (w<<8) + (kk<<5);
#pragma unroll
          for (int g = 0; g < 4; ++g){
            int rl = (g<<4) + ln;
            bf16x8 b = *(const bf16x8*)((const char*)Wl + rl*2048
                         + (((k0<<1) + (quad<<4)) ^ ((rl&7)<<4)));
            acc[g] = __builtin_amdgcn_mfma_f32_16x16x32_bf16(afr[kk], b, acc[g], 0, 0, 0);
          }
        }
#pragma unroll
        for (int g = 0; g < 4; ++g)
#pragma unroll
          for (int r = 0; r < 4; ++r)
            red[((w<<2)+g)*272 + ((quad<<2)+r)*17 + ln] = acc[g][r];
        __syncthreads();
        float gate[4];
#pragma unroll
        for (int g = 0; g < 4; ++g){
          float s = ihv[g];
#pragma unroll
          for (int w2 = 0; w2 < 4; ++w2) s += red[((w2<<2)+g)*272 + row*17 + jc];
          gate[g] = s;
        }
        float cn = sigmf(gate[1])*creg + expf(gate[0])*tanhf(gate[2]);
        float hn = sigmf(gate[3])*tanhf(cn);
        creg = cn;
        __bf16 hb16 = (__bf16)hn;
        st_coh2(h0seq + ((size_t)(t+1)<<14) + ((size_t)row<<10) + j0 + jc,
                (unsigned)__builtin_bit_cast(unsigned short, hb16));
        __syncthreads();   // red[] reuse guard for next tick
      }
      if (t < 256) gridbar(bar, (unsigned)(t+1), tid, 192);
    }
  } else {
    // ------------- layer 1: computes h1[t-1] at tick t (t>=1), slot t -------------
    const int j0 = (bid - 64) << 3;
    const int row = tid >> 3, jc = tid & 7;        // valid for tid<128
    const int t2c = jc >> 2, jl = jc & 3;
    float bgv[4] = {0,0,0,0};
    if (tid < 128){
#pragma unroll
      for (int g = 0; g < 4; ++g) bgv[g] = bg1[(g<<10) + j0 + jc];
    }
    for (int t = 0; t <= 256; ++t){
      if (t >= 1){
        const __bf16* ha = h0seq + ((size_t)t << 14);       // h0[t-1]
        const __bf16* hb = h1seq + ((size_t)(t-1) << 14);   // h1[t-2]
        bf16x8 af0[8], af1[8];
#pragma unroll
        for (int kk = 0; kk < 8; ++kk){
          int k0 = (w<<8) + (kk<<5);
          af0[kk] = ld_coh(ha + ((size_t)ln<<10) + k0 + (quad<<3));
          af1[kk] = ld_coh(hb + ((size_t)ln<<10) + k0 + (quad<<3));
        }
        asm volatile("s_waitcnt vmcnt(0)" ::: "memory");
        __builtin_amdgcn_sched_barrier(0);
        floatx4 acc[2] = {{0,0,0,0},{0,0,0,0}};
#pragma unroll
        for (int kk = 0; kk < 8; ++kk){
          int k0 = (w<<8) + (kk<<5);
#pragma unroll
          for (int t2 = 0; t2 < 2; ++t2){
            int rlA = (t2<<4) + ln;                 // Wih rows
            bf16x8 b0 = *(const bf16x8*)((const char*)Wl + rlA*2048
                          + (((k0<<1) + (quad<<4)) ^ ((rlA&7)<<4)));
            acc[t2] = __builtin_amdgcn_mfma_f32_16x16x32_bf16(af0[kk], b0, acc[t2], 0, 0, 0);
            int rlB = 32 + (t2<<4) + ln;            // Whh rows
            bf16x8 b1 = *(const bf16x8*)((const char*)Wl + rlB*2048
                          + (((k0<<1) + (quad<<4)) ^ ((rlB&7)<<4)));
            acc[t2] = __builtin_amdgcn_mfma_f32_16x16x32_bf16(af1[kk], b1, acc[t2], 0, 0, 0);
          }
        }
#pragma unroll
        for (int t2 = 0; t2 < 2; ++t2)
#pragma unroll
          for (int r = 0; r < 4; ++r)
            red[((w<<1)+t2)*272 + ((quad<<2)+r)*17 + ln] = acc[t2][r];
        __syncthreads();
        if (tid < 128){
          float gate[4];
#pragma unroll
          for (int g = 0; g < 4; ++g){
            int p = (g<<2) + jl;
            float s = bgv[g];
#pragma unroll
            for (int w2 = 0; w2 < 4; ++w2) s += red[((w2<<1)+t2c)*272 + row*17 + p];
            gate[g] = s;
          }
          float cn = sigmf(gate[1])*creg + expf(gate[0])*tanhf(gate[2]);
          float hn = sigmf(gate[3])*tanhf(cn);
          creg = cn;
          __bf16 hb16 = (__bf16)hn;
          st_coh2(h1seq + ((size_t)t<<14) + ((size_t)row<<10) + j0 + jc,
                  (unsigned)__builtin_bit_cast(unsigned short, hb16));
        }
        __syncthreads();   // red[] reuse guard
      }
      if (t < 256) gridbar(bar, (unsigned)(t+1), tid, 192);
    }
  }
}

// ---------- residual + layernorm (writes x f32 and bf16 in place) ----------
__global__ __launch_bounds__(256) void ln_kernel(const float* __restrict__ y,
    float* __restrict__ x, __bf16* __restrict__ xbf,
    const float* __restrict__ g, const float* __restrict__ b){
  int row = blockIdx.x, tid = threadIdx.x, lane = tid&63, w = tid>>6;
  size_t base = (size_t)row<<10;
  int k = tid<<2;
  float4 yv = *(const float4*)(y + base + k);
  float4 xv = *(const float4*)(x + base + k);
  float4 u = { yv.x+xv.x, yv.y+xv.y, yv.z+xv.z, yv.w+xv.w };
  float s = u.x+u.y+u.z+u.w;
  float q = u.x*u.x + u.y*u.y + u.z*u.z + u.w*u.w;
  for (int off = 32; off > 0; off >>= 1){
    s += __shfl_down(s, off, 64);
    q += __shfl_down(q, off, 64);
  }
  __shared__ float ss[4], qq[4];
  if (lane == 0){ ss[w] = s; qq[w] = q; }
  __syncthreads();
  float ts = ss[0]+ss[1]+ss[2]+ss[3];
  float tq = qq[0]+qq[1]+qq[2]+qq[3];
  float mean = ts*(1.0f/1024.0f);
  float var  = tq*(1.0f/1024.0f) - mean*mean;
  float inv  = rsqrtf(var + 1e-5f);
  float4 gv = *(const float4*)(g + k);
  float4 bv = *(const float4*)(b + k);
  float4 o = { (u.x-mean)*inv*gv.x + bv.x, (u.y-mean)*inv*gv.y + bv.y,
               (u.z-mean)*inv*gv.z + bv.z, (u.w-mean)*inv*gv.w + bv.w };
  *(float4*)(x + base + k) = o;
  bf16x4 ob = { (__bf16)o.x, (__bf16)o.y, (__bf16)o.z, (__bf16)o.w };
  *(bf16x4*)(xbf + base + k) = ob;
}

extern "C" void kernel_launch(void* const* d_in, const int* in_sizes, int n_in,
                              void* d_out, int out_size, void* d_ws, size_t ws_size,
                              hipStream_t stream){
  const int*   seq = (const int*)d_in[0];
  const float* emb = (const float*)d_in[1];
  const float* Wih = (const float*)d_in[2];
  const float* Whh = (const float*)d_in[3];
  const float* bg  = (const float*)d_in[4];
  const float* pW  = (const float*)d_in[5];
  const float* pb  = (const float*)d_in[6];
  const float* lng = (const float*)d_in[7];
  const float* lnb = (const float*)d_in[8];
  const float* oW  = (const float*)d_in[9];
  const float* ob  = (const float*)d_in[10];
  float* out = (float*)d_out;

  char* ws = (char*)d_ws;
  size_t off = 0;
  auto alloc = [&](size_t bytes)->char*{
    char* p = ws + off; off += (bytes + 255) & ~(size_t)255; return p;
  };
  __bf16* wih_bf = (__bf16*)alloc(16777216ULL*2);   // [2][2][4096][1024]
  __bf16* whh_bf = (__bf16*)alloc(16777216ULL*2);
  __bf16* pw_bf  = (__bf16*)alloc(2097152ULL*2);    // [2][1024][1024]
  __bf16* ow_bf  = (__bf16*)alloc(32768000ULL*2);   // [32000][1024]
  float*  x      = (float*)alloc(4194304ULL*4);     // [4096][1024] f32
  __bf16* xbf    = (__bf16*)alloc(4194304ULL*2);
  float*  ihb    = (float*)alloc(16777216ULL*4);    // [256][16][4096] f32
  __bf16* h0seq  = (__bf16*)alloc(257ULL*16384*2);  // [257][16][1024]
  __bf16* h1seq  = (__bf16*)alloc(257ULL*16384*2);
  float*  y      = (float*)alloc(4194304ULL*4);     // [4096][1024] f32
  unsigned* bar  = (unsigned*)alloc(256);           // [0]=cnt, [32]=gen

  cvt_kernel<<<16384, 256, 0, stream>>>(Wih, wih_bf, 4194304);
  cvt_kernel<<<16384, 256, 0, stream>>>(Whh, whh_bf, 4194304);
  cvt_kernel<<<2048,  256, 0, stream>>>(pW,  pw_bf,  524288);
  cvt_kernel<<<32000, 256, 0, stream>>>(oW,  ow_bf,  8192000);
  gather_kernel<<<4096, 256, 0, stream>>>(seq, emb, x, xbf);
  hipMemsetAsync(h0seq, 0, 16384*2, stream);   // slot 0 = zeros (stays zero)
  hipMemsetAsync(h1seq, 0, 16384*2, stream);

  for (int blk = 0; blk < 2; blk++){
    const __bf16* wih0 = wih_bf + (size_t)blk*2*4194304;
    const __bf16* wih1 = wih0 + 4194304;
    const __bf16* whh0 = whh_bf + (size_t)blk*2*4194304;
    const __bf16* whh1 = whh0 + 4194304;
    const float*  bg0  = bg + blk*2*4096;
    const float*  bg1  = bg0 + 4096;
    // ih0 = x @ Wih0^T + bg0  (layer-0 input projection, parallel over S)
    gemm_kernel<<<dim3(64,64), 256, 0, stream>>>(xbf, wih0, bg0, ihb, 4096, 0);
    hipMemsetAsync(bar, 0, 256, stream);
    // persistent recurrence: 257 ticks, weights LDS-resident, c-state in regs
    {
      const __bf16* p_whh0 = whh0;
      const __bf16* p_wih1 = wih1;
      const __bf16* p_whh1 = whh1;
      const float*  p_bg1  = bg1;
      const float*  p_ih   = ihb;
      __bf16* p_h0 = h0seq;
      __bf16* p_h1 = h1seq;
      unsigned* p_bar = bar;
      void* kargs[] = { &p_whh0, &p_wih1, &p_whh1, &p_bg1, &p_ih, &p_h0, &p_h1, &p_bar };
      hipLaunchCooperativeKernel((const void*)rec_kernel, dim3(192), dim3(256),
                                 kargs, 0, stream);
    }
    // y = gelu(h1 @ pW^T + pb); h1seq+16384 is dense [4096][1024] row-major
    gemm_kernel<<<dim3(16,64), 256, 0, stream>>>(h1seq + 16384, pw_bf + (size_t)blk*1048576,
                                                 pb + blk*1024, y, 1024, 1);
    ln_kernel<<<4096, 256, 0, stream>>>(y, x, xbf, lng + blk*1024, lnb + blk*1024);
  }
  // logits = x @ out_W^T + out_b, remapped to [B,S,V]
  gemm_kernel<<<dim3(500,64), 256, 0, stream>>>(xbf, ow_bf, ob, out, 32000, 2);
}

// Round 4
// 4571.833 us; speedup vs baseline: 6.1034x; 1.0412x over previous
//
#include <hip/hip_runtime.h>
#include <hip/hip_bf16.h>
#include <math.h>

// xLSTM forward on MI355X (gfx950).
// Recurrence: ONE persistent cooperative kernel per block (192 WGs):
//   - blocks 0..63   : layer0, 16 cell-cols each, Whh0 slice (128 KB) in LDS
//   - blocks 64..191 : layer1,  8 cell-cols each, Wih1+Whh1 slices (128 KB) in LDS
// Cross-block h traffic uses sc0/sc1 (coherence-point) loads/stores -> no cache
// maintenance anywhere in the tick loop.
// DECOUPLED barriers: layer0 syncs only among its 64 blocks (publishes monotone
// progress gen0); layer1 syncs among its 128 blocks and waits gen0 >= t (free
// once layer0 runs ahead; h slots are write-once so run-ahead is safe).
// h sequences: [slot][b][1024] bf16, slot s holds h[s-1] (slot 0 = zeros).

typedef __bf16 bf16x8 __attribute__((ext_vector_type(8)));
typedef __bf16 bf16x4 __attribute__((ext_vector_type(4)));
typedef float floatx4 __attribute__((ext_vector_type(4)));

__device__ __forceinline__ float sigmf(float x){ return 1.0f/(1.0f+expf(-x)); }

// ---- coherence-point accesses (bypass non-coherent L1/L2; cross-XCD safe) ----
__device__ __forceinline__ bf16x8 ld_coh(const __bf16* p){
  bf16x8 r;
  asm volatile("global_load_dwordx4 %0, %1, off sc0 sc1"
               : "=&v"(r) : "v"((unsigned long long)p));
  return r;   // NOT valid until s_waitcnt vmcnt(0)
}
__device__ __forceinline__ void st_coh2(__bf16* p, unsigned bits){
  asm volatile("global_store_short %0, %1, off sc0 sc1"
               :: "v"((unsigned long long)p), "v"(bits) : "memory");
}

// ---- flush-free sub-grid barrier (cnt at bar[0], gen at bar[32]) ----
// All h stores are sc0/sc1; the vmcnt(0) drain makes them globally visible
// before arrival. gen is MONOTONE (tick index) -> spin uses `< target`.
__device__ __forceinline__ void subbar(unsigned* bar, unsigned target, int tid, int nblk){
  asm volatile("s_waitcnt vmcnt(0)" ::: "memory");
  __syncthreads();
  if (tid == 0){
    unsigned prev = __hip_atomic_fetch_add(bar, 1u, __ATOMIC_RELAXED, __HIP_MEMORY_SCOPE_AGENT);
    if (prev == (unsigned)(nblk - 1)){
      __hip_atomic_store(bar, 0u, __ATOMIC_RELAXED, __HIP_MEMORY_SCOPE_AGENT);
      __hip_atomic_store(bar + 32, target, __ATOMIC_RELEASE, __HIP_MEMORY_SCOPE_AGENT);
    } else {
      while (__hip_atomic_load(bar + 32, __ATOMIC_RELAXED, __HIP_MEMORY_SCOPE_AGENT) < target)
        __builtin_amdgcn_s_sleep(2);
    }
  }
  __syncthreads();
}
__device__ __forceinline__ void wait_ge(const unsigned* gen, unsigned target, int tid){
  if (tid == 0){
    while (__hip_atomic_load(gen, __ATOMIC_RELAXED, __HIP_MEMORY_SCOPE_AGENT) < target)
      __builtin_amdgcn_s_sleep(2);
  }
  __syncthreads();
}

// ---------- f32 -> bf16 weight conversion (4 elems/thread) ----------
__global__ __launch_bounds__(256) void cvt_kernel(const float* __restrict__ src,
                                                  __bf16* __restrict__ dst, int n4){
  int i = blockIdx.x*256 + threadIdx.x;
  if (i >= n4) return;
  float4 v = ((const float4*)src)[i];
  bf16x4 o = { (__bf16)v.x, (__bf16)v.y, (__bf16)v.z, (__bf16)v.w };
  ((bf16x4*)dst)[i] = o;
}

// ---------- embedding gather: x[s*16+b][:] = emb[seq[b][s]][:] ----------
__global__ __launch_bounds__(256) void gather_kernel(const int* __restrict__ seq,
    const float* __restrict__ emb, float* __restrict__ x, __bf16* __restrict__ xbf){
  int r = blockIdx.x;                 // 0..4095, s = r>>4, b = r&15
  int tid = threadIdx.x;
  int tok = seq[((r&15)<<8) + (r>>4)];
  float4 v = *(const float4*)(emb + (size_t)tok*1024 + (tid<<2));
  *(float4*)(x + ((size_t)r<<10) + (tid<<2)) = v;
  bf16x4 o = { (__bf16)v.x, (__bf16)v.y, (__bf16)v.z, (__bf16)v.w };
  *(bf16x4*)(xbf + ((size_t)r<<10) + (tid<<2)) = o;
}

// ---------- 128x128-tile bf16 MFMA GEMM: C[4096, N] = A[4096,1024] @ B[N,1024]^T ----
// 4 waves in 2x2; each wave 64x64 (4x4 fragments, 16 MFMA/K-step).
// mode 0: out = acc + bias[col]                       (f32, row-major)
// mode 1: out = gelu_exact(acc + bias[col])           (f32, row-major)
// mode 2: out[(b*256+s)*N + col] = acc + bias[col]    (logits, [B,S,V] remap)
__global__ __launch_bounds__(256) void gemm128_kernel(const __bf16* __restrict__ A,
    const __bf16* __restrict__ Bw, const float* __restrict__ bias,
    float* __restrict__ out, int N, int mode){
  const int K = 1024;
  __shared__ __align__(16) __bf16 As[128][40];   // +8 pad -> 80B rows, 2-way max
  __shared__ __align__(16) __bf16 Bs[128][40];
  int m0 = blockIdx.y<<7, n0 = blockIdx.x<<7;
  int tid = threadIdx.x, w = tid>>6, lane = tid&63, quad = lane>>4, ln = lane&15;
  int wr = w>>1, wc = w&1;                       // wave -> 64x64 quadrant
  int srow = tid>>2, scol = (tid&3)<<3;          // staging: rows srow, srow+64
  const __bf16* ag = A  + (size_t)(m0+srow)*K + scol;
  const __bf16* bg = Bw + (size_t)(n0+srow)*K + scol;
  floatx4 acc[4][4];
#pragma unroll
  for (int m = 0; m < 4; m++)
#pragma unroll
    for (int n = 0; n < 4; n++) acc[m][n] = (floatx4){0.f,0.f,0.f,0.f};
  for (int kk = 0; kk < K; kk += 32){
    uint4 a0 = *(const uint4*)(ag + kk);
    uint4 a1 = *(const uint4*)(ag + (size_t)64*K + kk);
    uint4 b0 = *(const uint4*)(bg + kk);
    uint4 b1 = *(const uint4*)(bg + (size_t)64*K + kk);
    __syncthreads();
    *(uint4*)&As[srow][scol]    = a0;
    *(uint4*)&As[srow+64][scol] = a1;
    *(uint4*)&Bs[srow][scol]    = b0;
    *(uint4*)&Bs[srow+64][scol] = b1;
    __syncthreads();
    bf16x8 af[4], bf_[4];
#pragma unroll
    for (int m = 0; m < 4; m++) af[m]  = *(const bf16x8*)&As[(wr<<6)+(m<<4)+ln][quad<<3];
#pragma unroll
    for (int n = 0; n < 4; n++) bf_[n] = *(const bf16x8*)&Bs[(wc<<6)+(n<<4)+ln][quad<<3];
#pragma unroll
    for (int m = 0; m < 4; m++)
#pragma unroll
      for (int n = 0; n < 4; n++)
        acc[m][n] = __builtin_amdgcn_mfma_f32_16x16x32_bf16(af[m], bf_[n], acc[m][n], 0, 0, 0);
  }
#pragma unroll
  for (int n = 0; n < 4; n++){
    int col = n0 + (wc<<6) + (n<<4) + ln;
    float bv = bias[col];
#pragma unroll
    for (int m = 0; m < 4; m++)
#pragma unroll
      for (int r = 0; r < 4; r++){
        int row = m0 + (wr<<6) + (m<<4) + (quad<<2) + r;  // D: row=quad*4+reg, col=ln
        float v = acc[m][n][r] + bv;
        if (mode == 1) v = 0.5f*v*(1.0f + erff(v*0.70710678118f));
        size_t oidx;
        if (mode == 2){ int s = row>>4, b = row&15; oidx = ((size_t)((b<<8)+s))*N + col; }
        else oidx = (size_t)row*N + col;
        out[oidx] = v;
      }
  }
}

// ---------- persistent recurrence kernel (cooperative, 192 blocks x 256 thr) ----------
__global__ __launch_bounds__(256, 1) void rec_kernel(
    const __bf16* __restrict__ Whh0, const __bf16* __restrict__ Wih1,
    const __bf16* __restrict__ Whh1, const float* __restrict__ bg1,
    const float* __restrict__ ih, __bf16* __restrict__ h0seq,
    __bf16* __restrict__ h1seq, unsigned* bar){
  __shared__ __align__(16) __bf16 Wl[65536];   // 128 KB
  __shared__ float red[4352];                   // 16 tiles x [16][17] f32

  const int tid  = threadIdx.x;
  const int w    = tid >> 6, lane = tid & 63, quad = lane >> 4, ln = lane & 15;
  const int bid  = blockIdx.x;
  const bool is0 = (bid < 64);
  unsigned* bar0 = bar;        // layer0: cnt at [0], gen0 at [32]
  unsigned* bar1 = bar + 64;   // layer1: cnt at [64], gen1 at [96]

  // ---- stage weight slice into LDS, once (row-major, byte ^= (row&7)<<4) ----
  if (is0){
    const int j0 = bid << 4;
    for (int c = tid; c < 8192; c += 256){
      int rl = c >> 7, ks = c & 127;               // LDS row, 16B chunk within row
      int g = rl >> 4, jc = rl & 15;               // row rl = gate g, col j0+jc
      uint4 v = *(const uint4*)(Whh0 + (size_t)((g<<10) + j0 + jc)*1024 + (ks<<3));
      *(uint4*)((char*)Wl + rl*2048 + ((ks<<4) ^ ((rl&7)<<4))) = v;
    }
  } else {
    const int j0 = (bid - 64) << 3;
    for (int c = tid; c < 8192; c += 256){
      int rl = c >> 7, ks = c & 127;
      // rl = m*32 + t2*16 + p ; p = g*4 + jl ; global row = g*1024 + j0 + t2*4 + jl
      int m = rl >> 5, t2 = (rl >> 4) & 1, p = rl & 15, g = p >> 2, jl = p & 3;
      const __bf16* base = m ? Whh1 : Wih1;
      uint4 v = *(const uint4*)(base + (size_t)((g<<10) + j0 + (t2<<2) + jl)*1024 + (ks<<3));
      *(uint4*)((char*)Wl + rl*2048 + ((ks<<4) ^ ((rl&7)<<4))) = v;
    }
  }
  __syncthreads();

  float creg = 0.0f;   // register-resident cell state (one cell per thread)

  if (is0){
    // ---- layer 0: tick t computes h0[t] into slot t+1; never waits on layer1 ----
    const int j0 = bid << 4;
    const int row = tid >> 4, jc = tid & 15;       // this thread's cell
    for (int t = 0; t < 256; ++t){
      const __bf16* ha = h0seq + ((size_t)t << 14);   // h0[t-1]
      bf16x8 afr[8];
#pragma unroll
      for (int kk = 0; kk < 8; ++kk){
        int k0 = (w<<8) + (kk<<5);                // this wave's K slice
        afr[kk] = ld_coh(ha + ((size_t)ln<<10) + k0 + (quad<<3));
      }
      float ihv[4];                               // ih already includes bg0
      const float* ip = ih + (size_t)((t<<4) + row)*4096 + j0 + jc;
#pragma unroll
      for (int g = 0; g < 4; ++g) ihv[g] = ip[(size_t)g<<10];
      asm volatile("s_waitcnt vmcnt(0)" ::: "memory");
      __builtin_amdgcn_sched_barrier(0);
      floatx4 acc[4] = {{0,0,0,0},{0,0,0,0},{0,0,0,0},{0,0,0,0}};
#pragma unroll
      for (int kk = 0; kk < 8; ++kk){
        int k0 = (w<<8) + (kk<<5);
#pragma unroll
        for (int g = 0; g < 4; ++g){
          int rl = (g<<4) + ln;
          bf16x8 b = *(const bf16x8*)((const char*)Wl + rl*2048
                       + (((k0<<1) + (quad<<4)) ^ ((rl&7)<<4)));
          acc[g] = __builtin_amdgcn_mfma_f32_16x16x32_bf16(afr[kk], b, acc[g], 0, 0, 0);
        }
      }
#pragma unroll
      for (int g = 0; g < 4; ++g)
#pragma unroll
        for (int r = 0; r < 4; ++r)
          red[((w<<2)+g)*272 + ((quad<<2)+r)*17 + ln] = acc[g][r];
      __syncthreads();
      float gate[4];
#pragma unroll
      for (int g = 0; g < 4; ++g){
        float s = ihv[g];
#pragma unroll
        for (int w2 = 0; w2 < 4; ++w2) s += red[((w2<<2)+g)*272 + row*17 + jc];
        gate[g] = s;
      }
      float cn = sigmf(gate[1])*creg + expf(gate[0])*tanhf(gate[2]);
      float hn = sigmf(gate[3])*tanhf(cn);
      creg = cn;
      __bf16 hb16 = (__bf16)hn;
      st_coh2(h0seq + ((size_t)(t+1)<<14) + ((size_t)row<<10) + j0 + jc,
              (unsigned)__builtin_bit_cast(unsigned short, hb16));
      subbar(bar0, (unsigned)(t+1), tid, 64);   // publish gen0 = t+1
    }
  } else {
    // ---- layer 1: tick t (1..256) computes h1[t-1] into slot t; waits gen0>=t ----
    const int j0 = (bid - 64) << 3;
    const int row = tid >> 3, jc = tid & 7;        // valid for tid<128
    const int t2c = jc >> 2, jl = jc & 3;
    float bgv[4] = {0,0,0,0};
    if (tid < 128){
#pragma unroll
      for (int g = 0; g < 4; ++g) bgv[g] = bg1[(g<<10) + j0 + jc];
    }
    for (int t = 1; t <= 256; ++t){
      wait_ge(bar0 + 32, (unsigned)t, tid);             // h0 slot t available
      const __bf16* ha = h0seq + ((size_t)t << 14);     // h0[t-1]
      const __bf16* hb = h1seq + ((size_t)(t-1) << 14); // h1[t-2] (own gen1 >= t-1)
      bf16x8 af0[8], af1[8];
#pragma unroll
      for (int kk = 0; kk < 8; ++kk){
        int k0 = (w<<8) + (kk<<5);
        af0[kk] = ld_coh(ha + ((size_t)ln<<10) + k0 + (quad<<3));
        af1[kk] = ld_coh(hb + ((size_t)ln<<10) + k0 + (quad<<3));
      }
      asm volatile("s_waitcnt vmcnt(0)" ::: "memory");
      __builtin_amdgcn_sched_barrier(0);
      floatx4 acc[2] = {{0,0,0,0},{0,0,0,0}};
#pragma unroll
      for (int kk = 0; kk < 8; ++kk){
        int k0 = (w<<8) + (kk<<5);
#pragma unroll
        for (int t2 = 0; t2 < 2; ++t2){
          int rlA = (t2<<4) + ln;                 // Wih rows
          bf16x8 b0 = *(const bf16x8*)((const char*)Wl + rlA*2048
                        + (((k0<<1) + (quad<<4)) ^ ((rlA&7)<<4)));
          acc[t2] = __builtin_amdgcn_mfma_f32_16x16x32_bf16(af0[kk], b0, acc[t2], 0, 0, 0);
          int rlB = 32 + (t2<<4) + ln;            // Whh rows
          bf16x8 b1 = *(const bf16x8*)((const char*)Wl + rlB*2048
                        + (((k0<<1) + (quad<<4)) ^ ((rlB&7)<<4)));
          acc[t2] = __builtin_amdgcn_mfma_f32_16x16x32_bf16(af1[kk], b1, acc[t2], 0, 0, 0);
        }
      }
#pragma unroll
      for (int t2 = 0; t2 < 2; ++t2)
#pragma unroll
        for (int r = 0; r < 4; ++r)
          red[((w<<1)+t2)*272 + ((quad<<2)+r)*17 + ln] = acc[t2][r];
      __syncthreads();
      if (tid < 128){
        float gate[4];
#pragma unroll
        for (int g = 0; g < 4; ++g){
          int p = (g<<2) + jl;
          float s = bgv[g];
#pragma unroll
          for (int w2 = 0; w2 < 4; ++w2) s += red[((w2<<1)+t2c)*272 + row*17 + p];
          gate[g] = s;
        }
        float cn = sigmf(gate[1])*creg + expf(gate[0])*tanhf(gate[2]);
        float hn = sigmf(gate[3])*tanhf(cn);
        creg = cn;
        __bf16 hb16 = (__bf16)hn;
        st_coh2(h1seq + ((size_t)t<<14) + ((size_t)row<<10) + j0 + jc,
                (unsigned)__builtin_bit_cast(unsigned short, hb16));
      }
      subbar(bar1, (unsigned)t, tid, 128);        // publish gen1 = t
    }
  }
}

// ---------- residual + layernorm (writes x f32 and bf16 in place) ----------
__global__ __launch_bounds__(256) void ln_kernel(const float* __restrict__ y,
    float* __restrict__ x, __bf16* __restrict__ xbf,
    const float* __restrict__ g, const float* __restrict__ b){
  int row = blockIdx.x, tid = threadIdx.x, lane = tid&63, w = tid>>6;
  size_t base = (size_t)row<<10;
  int k = tid<<2;
  float4 yv = *(const float4*)(y + base + k);
  float4 xv = *(const float4*)(x + base + k);
  float4 u = { yv.x+xv.x, yv.y+xv.y, yv.z+xv.z, yv.w+xv.w };
  float s = u.x+u.y+u.z+u.w;
  float q = u.x*u.x + u.y*u.y + u.z*u.z + u.w*u.w;
  for (int off = 32; off > 0; off >>= 1){
    s += __shfl_down(s, off, 64);
    q += __shfl_down(q, off, 64);
  }
  __shared__ float ss[4], qq[4];
  if (lane == 0){ ss[w] = s; qq[w] = q; }
  __syncthreads();
  float ts = ss[0]+ss[1]+ss[2]+ss[3];
  float tq = qq[0]+qq[1]+qq[2]+qq[3];
  float mean = ts*(1.0f/1024.0f);
  float var  = tq*(1.0f/1024.0f) - mean*mean;
  float inv  = rsqrtf(var + 1e-5f);
  float4 gv = *(const float4*)(g + k);
  float4 bv = *(const float4*)(b + k);
  float4 o = { (u.x-mean)*inv*gv.x + bv.x, (u.y-mean)*inv*gv.y + bv.y,
               (u.z-mean)*inv*gv.z + bv.z, (u.w-mean)*inv*gv.w + bv.w };
  *(float4*)(x + base + k) = o;
  bf16x4 ob = { (__bf16)o.x, (__bf16)o.y, (__bf16)o.z, (__bf16)o.w };
  *(bf16x4*)(xbf + base + k) = ob;
}

extern "C" void kernel_launch(void* const* d_in, const int* in_sizes, int n_in,
                              void* d_out, int out_size, void* d_ws, size_t ws_size,
                              hipStream_t stream){
  const int*   seq = (const int*)d_in[0];
  const float* emb = (const float*)d_in[1];
  const float* Wih = (const float*)d_in[2];
  const float* Whh = (const float*)d_in[3];
  const float* bg  = (const float*)d_in[4];
  const float* pW  = (const float*)d_in[5];
  const float* pb  = (const float*)d_in[6];
  const float* lng = (const float*)d_in[7];
  const float* lnb = (const float*)d_in[8];
  const float* oW  = (const float*)d_in[9];
  const float* ob  = (const float*)d_in[10];
  float* out = (float*)d_out;

  char* ws = (char*)d_ws;
  size_t off = 0;
  auto alloc = [&](size_t bytes)->char*{
    char* p = ws + off; off += (bytes + 255) & ~(size_t)255; return p;
  };
  __bf16* wih_bf = (__bf16*)alloc(16777216ULL*2);   // [2][2][4096][1024]
  __bf16* whh_bf = (__bf16*)alloc(16777216ULL*2);
  __bf16* pw_bf  = (__bf16*)alloc(2097152ULL*2);    // [2][1024][1024]
  __bf16* ow_bf  = (__bf16*)alloc(32768000ULL*2);   // [32000][1024]
  float*  x      = (float*)alloc(4194304ULL*4);     // [4096][1024] f32
  __bf16* xbf    = (__bf16*)alloc(4194304ULL*2);
  float*  ihb    = (float*)alloc(16777216ULL*4);    // [256][16][4096] f32
  __bf16* h0seq  = (__bf16*)alloc(257ULL*16384*2);  // [257][16][1024]
  __bf16* h1seq  = (__bf16*)alloc(257ULL*16384*2);
  float*  y      = (float*)alloc(4194304ULL*4);     // [4096][1024] f32
  unsigned* bar  = (unsigned*)alloc(512);           // [0]=cnt0,[32]=gen0,[64]=cnt1,[96]=gen1

  cvt_kernel<<<16384, 256, 0, stream>>>(Wih, wih_bf, 4194304);
  cvt_kernel<<<16384, 256, 0, stream>>>(Whh, whh_bf, 4194304);
  cvt_kernel<<<2048,  256, 0, stream>>>(pW,  pw_bf,  524288);
  cvt_kernel<<<32000, 256, 0, stream>>>(oW,  ow_bf,  8192000);
  gather_kernel<<<4096, 256, 0, stream>>>(seq, emb, x, xbf);
  hipMemsetAsync(h0seq, 0, 16384*2, stream);   // slot 0 = zeros (stays zero)
  hipMemsetAsync(h1seq, 0, 16384*2, stream);

  for (int blk = 0; blk < 2; blk++){
    const __bf16* wih0 = wih_bf + (size_t)blk*2*4194304;
    const __bf16* wih1 = wih0 + 4194304;
    const __bf16* whh0 = whh_bf + (size_t)blk*2*4194304;
    const __bf16* whh1 = whh0 + 4194304;
    const float*  bg0  = bg + blk*2*4096;
    const float*  bg1  = bg0 + 4096;
    // ih0 = x @ Wih0^T + bg0  (layer-0 input projection, parallel over S)
    gemm128_kernel<<<dim3(32,32), 256, 0, stream>>>(xbf, wih0, bg0, ihb, 4096, 0);
    hipMemsetAsync(bar, 0, 512, stream);
    // persistent recurrence: decoupled layer barriers, weights LDS-resident
    {
      const __bf16* p_whh0 = whh0;
      const __bf16* p_wih1 = wih1;
      const __bf16* p_whh1 = whh1;
      const float*  p_bg1  = bg1;
      const float*  p_ih   = ihb;
      __bf16* p_h0 = h0seq;
      __bf16* p_h1 = h1seq;
      unsigned* p_bar = bar;
      void* kargs[] = { &p_whh0, &p_wih1, &p_whh1, &p_bg1, &p_ih, &p_h0, &p_h1, &p_bar };
      hipLaunchCooperativeKernel((const void*)rec_kernel, dim3(192), dim3(256),
                                 kargs, 0, stream);
    }
    // y = gelu(h1 @ pW^T + pb); h1seq+16384 is dense [4096][1024] row-major
    gemm128_kernel<<<dim3(8,32), 256, 0, stream>>>(h1seq + 16384, pw_bf + (size_t)blk*1048576,
                                                   pb + blk*1024, y, 1024, 1);
    ln_kernel<<<4096, 256, 0, stream>>>(y, x, xbf, lng + blk*1024, lnb + blk*1024);
  }
  // logits = x @ out_W^T + out_b, remapped to [B,S,V]
  gemm128_kernel<<<dim3(250,32), 256, 0, stream>>>(xbf, ow_bf, ob, out, 32000, 2);
}